// Round 4
// baseline (352.070 us; speedup 1.0000x reference)
//
#include <hip/hip_runtime.h>

// ---------------- problem constants ----------------
#define DIMX  4096
#define NH    32
#define HD    128
#define BB    2
#define TT    1024
#define MROWS (BB*TT)          // 2048
#define CQKV  3072             // compact qkv cols: 1024 q_red | 1024 k | 1024 v
// (1/sqrt(128)) * log2(e): lets attention use exp2 directly
#define SCALE_Q 0.12751743f

typedef _Float16 half_t;
typedef __attribute__((ext_vector_type(4))) _Float16 f16x4;
typedef __attribute__((ext_vector_type(8))) _Float16 f16x8;
typedef __attribute__((ext_vector_type(4))) float    f32x4;

// async global->LDS, 16B/lane; LDS dest = wave-uniform base + lane*16
__device__ __forceinline__ void async_copy16(const void* gsrc, void* ldst) {
  __builtin_amdgcn_global_load_lds(
      (const __attribute__((address_space(1))) unsigned int*)gsrc,
      (__attribute__((address_space(3))) unsigned int*)ldst,
      16, 0, 0);
}

// ---------------- fp32 -> fp16 conversion ----------------
__global__ __launch_bounds__(256) void cvt_f32_f16_kernel(
    const float4* __restrict__ src, f16x4* __restrict__ dst, int n4) {
  int stride = gridDim.x * blockDim.x;
  for (int i = blockIdx.x * blockDim.x + threadIdx.x; i < n4; i += stride) {
    float4 f = src[i];
    f16x4 h;
    h.x = (_Float16)f.x; h.y = (_Float16)f.y;
    h.z = (_Float16)f.z; h.w = (_Float16)f.w;
    dst[i] = h;
  }
}

// ---------------- fold W1 -> W1f [3072][4096] fp16, b1f [3072] f32 ----------
// rows 0..1023:  q_red rows = (sum of 4 q rows) * SCALE_Q
// rows 1024..3071: k/v rows copied (W1 row = row + 3072)
__global__ __launch_bounds__(256) void fold_w1_kernel(
    const float* __restrict__ W1, const float* __restrict__ b1,
    half_t* __restrict__ W1f, float* __restrict__ b1f)
{
  long idx = (long)blockIdx.x * 256 + threadIdx.x;   // 3072*1024
  int row = (int)(idx >> 10);
  int c4  = ((int)idx & 1023) << 2;
  f16x4 h;
  if (row < 1024) {
    const float* s = W1 + ((long)row << 2) * DIMX + c4;
    float4 a = *(const float4*)s;
    float4 b = *(const float4*)(s + DIMX);
    float4 c = *(const float4*)(s + 2 * DIMX);
    float4 d = *(const float4*)(s + 3 * DIMX);
    h.x = (_Float16)((a.x + b.x + c.x + d.x) * SCALE_Q);
    h.y = (_Float16)((a.y + b.y + c.y + d.y) * SCALE_Q);
    h.z = (_Float16)((a.z + b.z + c.z + d.z) * SCALE_Q);
    h.w = (_Float16)((a.w + b.w + c.w + d.w) * SCALE_Q);
    if (c4 == 0) {
      const float* bb = b1 + ((long)row << 2);
      b1f[row] = (bb[0] + bb[1] + bb[2] + bb[3]) * SCALE_Q;
    }
  } else {
    const float* s = W1 + ((long)(row + 3072)) * DIMX + c4;
    float4 a = *(const float4*)s;
    h.x = (_Float16)a.x; h.y = (_Float16)a.y;
    h.z = (_Float16)a.z; h.w = (_Float16)a.w;
    if (c4 == 0) b1f[row] = b1[row + 3072];
  }
  *(f16x4*)&W1f[(long)row * DIMX + c4] = h;
}

// ---------------- fold W2 -> W2f [4096][1024] fp16 ----------------
// W2f[n][j] = sum_{r<4} W2[n][4j+r]
__global__ __launch_bounds__(256) void fold_w2_kernel(
    const float* __restrict__ W2, half_t* __restrict__ W2f)
{
  long idx = (long)blockIdx.x * 256 + threadIdx.x;   // 4096*256
  int row = (int)(idx >> 8);
  int j4  = ((int)idx & 255) << 2;
  const float* s = W2 + (long)row * DIMX + ((long)j4 << 2);
  float4 a = *(const float4*)s;
  float4 b = *(const float4*)(s + 4);
  float4 c = *(const float4*)(s + 8);
  float4 d = *(const float4*)(s + 12);
  f16x4 h;
  h.x = (_Float16)(a.x + a.y + a.z + a.w);
  h.y = (_Float16)(b.x + b.y + b.z + b.w);
  h.z = (_Float16)(c.x + c.y + c.z + c.w);
  h.w = (_Float16)(d.x + d.y + d.z + d.w);
  *(f16x4*)&W2f[(long)row * 1024 + j4] = h;
}

// ============================================================================
// NT GEMM core, BK=64 + XOR chunk swizzle (T2, both-sides: rule #21).
// Tile 128x128, 4 waves 2x2, each wave 64x64 = 4x4 mfma_16x16x32 per kk.
// R3 verified: SQ_LDS_BANK_CONFLICT = 0, 810 TF (~90% of 2-barrier ceiling).
// ============================================================================

// ---------------- split-K NT GEMM (GEMM1): 2 K-slices, f32 partials --------
// grid (N/128, M/128, 2) = 768 blocks = 3/CU.
__global__ __launch_bounds__(256, 3) void gemm_nt_splitk(
    const half_t* __restrict__ A, const half_t* __restrict__ Bw,
    float* __restrict__ Cp0, float* __restrict__ Cp1,
    int M, int N, int K)
{
  __shared__ alignas(16) half_t As[128 * 64];   // 16 KB
  __shared__ alignas(16) half_t Bs[128 * 64];   // 16 KB

  const int tid  = threadIdx.x;
  const int lane = tid & 63;
  const int w    = tid >> 6;
  const long row0 = (long)blockIdx.y * 128;
  const long col0 = (long)blockIdx.x * 128;
  const int  KH   = K >> 1;
  const long k0   = (long)blockIdx.z * KH;

  // staging: thread t -> rows {i*32 + (t>>3)}, source chunk (t&7)^(row&7)
  const int rr = tid >> 3;                       // 0..31
  const int cs = (((tid & 7) ^ (rr & 7)) << 3);  // swizzled col (halves)
  const half_t* ga[4]; const half_t* gb[4];
#pragma unroll
  for (int i = 0; i < 4; ++i) {
    ga[i] = A  + (row0 + i * 32 + rr) * K + k0 + cs;
    gb[i] = Bw + (col0 + i * 32 + rr) * K + k0 + cs;
  }
  half_t* lds_a = &As[w * 512];   // + i*2048; HW adds lane*16B (linear) ✓
  half_t* lds_b = &Bs[w * 512];

  // wave 2x2: wave w owns C[wm..wm+63][wn..wn+63]
  const int wm = (w >> 1) * 64;
  const int wn = (w & 1) * 64;
  const int fr   = lane & 15;
  const int quad = lane >> 4;
  const int rsw  = fr & 7;
  const int o0 = ((quad ^ rsw) << 3);            // kk=0  chunk (halves)
  const int o1 = (((quad | 4) ^ rsw) << 3);      // kk=32 chunk
  const half_t* paw = &As[(wm + fr) * 64];
  const half_t* pbw = &Bs[(wn + fr) * 64];

  f32x4 acc[4][4] = {};

  for (int kt = 0; kt < KH; kt += 64) {
    __syncthreads();
#pragma unroll
    for (int i = 0; i < 4; ++i) async_copy16(ga[i] + kt, lds_a + i * 2048);
#pragma unroll
    for (int i = 0; i < 4; ++i) async_copy16(gb[i] + kt, lds_b + i * 2048);
    __syncthreads();   // compiler drains vmcnt(0) before s_barrier

    f16x8 af[4], bf[4];
#pragma unroll
    for (int mi = 0; mi < 4; ++mi) af[mi] = *(const f16x8*)(paw + mi * 1024 + o0);
#pragma unroll
    for (int ni = 0; ni < 4; ++ni) bf[ni] = *(const f16x8*)(pbw + ni * 1024 + o0);
#pragma unroll
    for (int mi = 0; mi < 4; ++mi)
#pragma unroll
      for (int ni = 0; ni < 4; ++ni)
        acc[mi][ni] = __builtin_amdgcn_mfma_f32_16x16x32_f16(
            af[mi], bf[ni], acc[mi][ni], 0, 0, 0);

#pragma unroll
    for (int mi = 0; mi < 4; ++mi) af[mi] = *(const f16x8*)(paw + mi * 1024 + o1);
#pragma unroll
    for (int ni = 0; ni < 4; ++ni) bf[ni] = *(const f16x8*)(pbw + ni * 1024 + o1);
#pragma unroll
    for (int mi = 0; mi < 4; ++mi)
#pragma unroll
      for (int ni = 0; ni < 4; ++ni)
        acc[mi][ni] = __builtin_amdgcn_mfma_f32_16x16x32_f16(
            af[mi], bf[ni], acc[mi][ni], 0, 0, 0);
  }

  float* Cp = blockIdx.z ? Cp1 : Cp0;
  // C/D layout: col = lane&15, row = (lane>>4)*4 + r
  const int er = (lane >> 4) * 4;
  const int ec = lane & 15;
#pragma unroll
  for (int mi = 0; mi < 4; ++mi) {
#pragma unroll
    for (int ni = 0; ni < 4; ++ni) {
      long gn = col0 + wn + ni * 16 + ec;
#pragma unroll
      for (int r = 0; r < 4; ++r) {
        long gm = row0 + wm + mi * 16 + er + r;
        Cp[gm * N + gn] = acc[mi][ni][r];
      }
    }
  }
}

// ---------------- plain NT GEMM + bias (GEMM2) -----------------------------
// Same BK=64 swizzled body; grid (N/128, M/128) = 512 blocks (even 2/CU).
template<int OUT_IS_F16>
__global__ __launch_bounds__(256, 3) void gemm_nt_bias(
    const half_t* __restrict__ A, const half_t* __restrict__ Bw,
    const float* __restrict__ bias, void* __restrict__ Cout,
    int M, int N, int K)
{
  __shared__ alignas(16) half_t As[128 * 64];   // 16 KB
  __shared__ alignas(16) half_t Bs[128 * 64];   // 16 KB

  const int tid  = threadIdx.x;
  const int lane = tid & 63;
  const int w    = tid >> 6;
  const long row0 = (long)blockIdx.y * 128;
  const long col0 = (long)blockIdx.x * 128;

  const int rr = tid >> 3;
  const int cs = (((tid & 7) ^ (rr & 7)) << 3);
  const half_t* ga[4]; const half_t* gb[4];
#pragma unroll
  for (int i = 0; i < 4; ++i) {
    ga[i] = A  + (row0 + i * 32 + rr) * K + cs;
    gb[i] = Bw + (col0 + i * 32 + rr) * K + cs;
  }
  half_t* lds_a = &As[w * 512];
  half_t* lds_b = &Bs[w * 512];

  const int wm = (w >> 1) * 64;
  const int wn = (w & 1) * 64;
  const int fr   = lane & 15;
  const int quad = lane >> 4;
  const int rsw  = fr & 7;
  const int o0 = ((quad ^ rsw) << 3);
  const int o1 = (((quad | 4) ^ rsw) << 3);
  const half_t* paw = &As[(wm + fr) * 64];
  const half_t* pbw = &Bs[(wn + fr) * 64];

  f32x4 acc[4][4] = {};

  for (int kt = 0; kt < K; kt += 64) {
    __syncthreads();
#pragma unroll
    for (int i = 0; i < 4; ++i) async_copy16(ga[i] + kt, lds_a + i * 2048);
#pragma unroll
    for (int i = 0; i < 4; ++i) async_copy16(gb[i] + kt, lds_b + i * 2048);
    __syncthreads();

    f16x8 af[4], bf[4];
#pragma unroll
    for (int mi = 0; mi < 4; ++mi) af[mi] = *(const f16x8*)(paw + mi * 1024 + o0);
#pragma unroll
    for (int ni = 0; ni < 4; ++ni) bf[ni] = *(const f16x8*)(pbw + ni * 1024 + o0);
#pragma unroll
    for (int mi = 0; mi < 4; ++mi)
#pragma unroll
      for (int ni = 0; ni < 4; ++ni)
        acc[mi][ni] = __builtin_amdgcn_mfma_f32_16x16x32_f16(
            af[mi], bf[ni], acc[mi][ni], 0, 0, 0);

#pragma unroll
    for (int mi = 0; mi < 4; ++mi) af[mi] = *(const f16x8*)(paw + mi * 1024 + o1);
#pragma unroll
    for (int ni = 0; ni < 4; ++ni) bf[ni] = *(const f16x8*)(pbw + ni * 1024 + o1);
#pragma unroll
    for (int mi = 0; mi < 4; ++mi)
#pragma unroll
      for (int ni = 0; ni < 4; ++ni)
        acc[mi][ni] = __builtin_amdgcn_mfma_f32_16x16x32_f16(
            af[mi], bf[ni], acc[mi][ni], 0, 0, 0);
  }

  const int er = (lane >> 4) * 4;
  const int ec = lane & 15;
#pragma unroll
  for (int mi = 0; mi < 4; ++mi) {
#pragma unroll
    for (int ni = 0; ni < 4; ++ni) {
      long gn = col0 + wn + ni * 16 + ec;
      float bv = bias[gn];
#pragma unroll
      for (int r = 0; r < 4; ++r) {
        long gm = row0 + wm + mi * 16 + er + r;
        float v = acc[mi][ni][r] + bv;
        if (OUT_IS_F16) ((half_t*)Cout)[gm * N + gn] = (half_t)v;
        else            ((float*)Cout)[gm * N + gn]  = v;
      }
    }
  }
}

// ---------------- split-K reduce: qkvc = f16(C0 + C1 + bias) ---------------
// grid (N/4/256, M) = (3, 2048); one float4 per thread; partials are L3-hot.
__global__ __launch_bounds__(256) void splitk_reduce_kernel(
    const float4* __restrict__ C0, const float4* __restrict__ C1,
    const float4* __restrict__ bias4, f16x4* __restrict__ dst)
{
  const int col  = blockIdx.x * 256 + threadIdx.x;   // 0..767 (N/4)
  const long row = blockIdx.y;                       // 0..2047
  const long i   = row * (CQKV / 4) + col;
  float4 a = C0[i];
  float4 b = C1[i];
  float4 bv = bias4[col];
  f16x4 h;
  h.x = (_Float16)(a.x + b.x + bv.x);
  h.y = (_Float16)(a.y + b.y + bv.y);
  h.z = (_Float16)(a.z + b.z + bv.z);
  h.w = (_Float16)(a.w + b.w + bv.w);
  dst[i] = h;
}

// ---------------- V transpose: qkvc v-part -> vt[b][1024 d][1024 tok] ------
// LDS-tiled 64x64; runs after GEMM1 consumed xh, writes into the xh buffer.
__global__ __launch_bounds__(256) void v_transpose_kernel(
    const half_t* __restrict__ qkvc, half_t* __restrict__ vt)
{
  __shared__ half_t lt[64][72];
  const int t  = threadIdx.x;
  const int b  = blockIdx.z;
  const int d0 = blockIdx.x * 64;      // dim tile
  const int k0 = blockIdx.y * 64;      // token tile
  const int tl = t >> 3;               // 0..31
  const int dc = (t & 7) * 8;          // 0..56

  const half_t* src = qkvc + ((long)b * TT + k0 + tl) * CQKV + 2048 + d0 + dc;
  *(f16x8*)&lt[tl][dc]      = *(const f16x8*)src;
  *(f16x8*)&lt[tl + 32][dc] = *(const f16x8*)(src + 32 * CQKV);
  __syncthreads();

  half_t* dstp = vt + ((long)b * 1024 + d0 + tl) * 1024 + k0 + dc;
  f16x8 o0, o1;
#pragma unroll
  for (int j = 0; j < 8; ++j) {
    o0[j] = lt[dc + j][tl];
    o1[j] = lt[dc + j][tl + 32];
  }
  *(f16x8*)dstp = o0;
  *(f16x8*)(dstp + 32 * 1024) = o1;
}

// ---------------- MFMA flash attention (compact 32-dim heads) --------------
// Block: 256 thr = 4 waves; wave w owns 16 queries. Grid (16, B*NH).
// Per 64-key chunk: K and V staged with ONE async_copy16 each into
// XOR-swizzled packed LDS (rule #21: linear dest + swizzled SOURCE +
// matching swizzled read):
//   Ks [32 u][8 chunks]: u = key>>1; stored pos p holds global chunk
//     p^(u&7), global chunk g = (key&1)*4 + d_chunk  -> perfect 2-way reads.
//   Vs [32 d][8 chunks]: stored pos p holds key-chunk p^(d&7)        -> 2-way.
// l[q] via all-ones A-fragment MFMA (no LDS ones row, no __shfl).
#define PSS 72
__global__ __launch_bounds__(256, 4) void attn_kernel(
    const half_t* __restrict__ qkv,  // [MROWS][3072]
    const half_t* __restrict__ vt,   // [BB][1024 d][1024 tok]
    half_t* __restrict__ attc)       // [MROWS][1024]
{
  __shared__ alignas(16) half_t Ks[32 * 64];        // 4 KB
  __shared__ alignas(16) half_t Vs[32 * 64];        // 4 KB
  __shared__ alignas(16) half_t Ps[4][16 * PSS];    // per-wave [q][key]

  const int tid  = threadIdx.x;
  const int lane = tid & 63;
  const int w    = tid >> 6;
  const int low  = lane & 15;
  const int quad = lane >> 4;
  const int bh   = blockIdx.y;
  const int b    = bh >> 5;
  const int h    = bh & 31;
  const long rb  = (long)b * TT;

  // staging source addresses (per thread); LDS dest linear: t -> t*16B
  const int su  = tid >> 3;              // LDS row (K: u=key>>1, V: d)
  const int sp  = tid & 7;               // stored chunk position
  const int spx = sp ^ (su & 7);         // source chunk
  // K: key = 2u + (spx>>2), d-chunk = spx&3
  const half_t* kg = qkv + (rb + 2 * su + (spx >> 2)) * CQKV + 1024
                         + h * 32 + (spx & 3) * 8;
  // V: vt row d = h*32 + su, key offset spx*8
  const half_t* vg = vt + ((long)b * 1024 + h * 32 + su) * 1024 + spx * 8;
  half_t* kdst = &Ks[w * 512];           // wave-uniform; HW adds lane*16B
  half_t* vdst = &Vs[w * 512];
  half_t* psw  = &Ps[w][0];
  float*  Ob   = (float*)psw;            // epilogue overlay [q][36 floats]

  const int tile = blockIdx.x;
  const int t0   = tile * 64;
  const int qg   = t0 + 16 * w;

  // Q fragment: A[m=low][k=quad*8+j]
  f16x8 qf = *(const f16x8*)&qkv[(rb + qg + low) * CQKV + h * 32 + quad * 8];

  // all-ones A-fragment: D[m][n] = sum_k P[n][k] = l[n] for every m
  f16x8 onesf;
#pragma unroll
  for (int i = 0; i < 8; ++i) onesf[i] = (_Float16)1.0f;

  f32x4 acc0 = {}, acc1 = {}, acc2 = {};
  const f32x4 zero = {};

  const int dsw = low & 7;
  const int ksw = (low >> 1) & 7;
  const int kp  = (((low & 1) << 2) | quad) ^ ksw;   // Ks read chunk pos

  for (int c = 0; c <= t0; c += 64) {
    __syncthreads();
    async_copy16(kg + (long)c * CQKV, kdst);
    async_copy16(vg + c, vdst);
    __syncthreads();

    // S = Q.K^T : C[m=q][n=key]
    f32x4 s[4];
#pragma unroll
    for (int st = 0; st < 4; ++st) {
      const int u = st * 8 + (low >> 1);
      f16x8 kf = *(const f16x8*)&Ks[u * 64 + kp * 8];
      s[st] = __builtin_amdgcn_mfma_f32_16x16x32_f16(qf, kf, zero, 0, 0, 0);
    }

    // P = exp2(S) (causal mask only at diagonal chunk), write to LDS
    const bool diag = (c == t0);
#pragma unroll
    for (int st = 0; st < 4; ++st) {
#pragma unroll
      for (int r = 0; r < 4; ++r) {
        const int key = c + st * 16 + low;
        const int q   = qg + 4 * quad + r;
        float p = __builtin_amdgcn_exp2f(s[st][r]);
        if (diag && key > q) p = 0.f;
        psw[(4 * quad + r) * PSS + st * 16 + low] = (_Float16)p;
      }
    }

    // P frags (B: [n=q][k=key])
    f16x8 p0 = *(const f16x8*)&psw[low * PSS + 0 * 32 + quad * 8];
    f16x8 p1 = *(const f16x8*)&psw[low * PSS + 1 * 32 + quad * 8];

    // Vs frags (A: [m=d][k=key]), swizzled chunk reads
    f16x8 v00 = *(const f16x8*)&Vs[(0  + low) * 64 + ((0 + quad) ^ dsw) * 8];
    f16x8 v01 = *(const f16x8*)&Vs[(0  + low) * 64 + ((4 + quad) ^ dsw) * 8];
    f16x8 v10 = *(const f16x8*)&Vs[(16 + low) * 64 + ((0 + quad) ^ dsw) * 8];
    f16x8 v11 = *(const f16x8*)&Vs[(16 + low) * 64 + ((4 + quad) ^ dsw) * 8];

    acc0 = __builtin_amdgcn_mfma_f32_16x16x32_f16(v00,   p0, acc0, 0, 0, 0);
    acc0 = __builtin_amdgcn_mfma_f32_16x16x32_f16(v01,   p1, acc0, 0, 0, 0);
    acc1 = __builtin_amdgcn_mfma_f32_16x16x32_f16(v10,   p0, acc1, 0, 0, 0);
    acc1 = __builtin_amdgcn_mfma_f32_16x16x32_f16(v11,   p1, acc1, 0, 0, 0);
    acc2 = __builtin_amdgcn_mfma_f32_16x16x32_f16(onesf, p0, acc2, 0, 0, 0);
    acc2 = __builtin_amdgcn_mfma_f32_16x16x32_f16(onesf, p1, acc2, 0, 0, 0);
  }

  // ---- epilogue ----
  __syncthreads();   // last chunk's Ps reads done before Ob overlay writes

  // every lane's acc2[r] = l[q = lane&15]
  float linv = 1.0f / acc2[0];

  // O^T[d=16t+4quad+r][q=low] -> Ob[q][d], scaled
#pragma unroll
  for (int r = 0; r < 4; ++r) {
    Ob[low * 36 + 0  + 4 * quad + r] = acc0[r] * linv;
    Ob[low * 36 + 16 + 4 * quad + r] = acc1[r] * linv;
  }
  __syncthreads();

  // row-wise readback: lane (q=low, dblk=quad) -> 8 contiguous dims
  f16x8 ov;
#pragma unroll
  for (int i = 0; i < 8; ++i)
    ov[i] = (_Float16)Ob[low * 36 + quad * 8 + i];
  *(f16x8*)&attc[(rb + qg + low) * 1024 + h * 32 + quad * 8] = ov;
}

// ---------------- launcher ----------------
extern "C" void kernel_launch(void* const* d_in, const int* in_sizes, int n_in,
                              void* d_out, int out_size, void* d_ws, size_t ws_size,
                              hipStream_t stream) {
  (void)in_sizes; (void)n_in; (void)out_size; (void)ws_size;
  const float* x  = (const float*)d_in[0];
  const float* W1 = (const float*)d_in[1];
  const float* b1 = (const float*)d_in[2];
  const float* W2 = (const float*)d_in[3];
  const float* b2 = (const float*)d_in[4];
  float* out = (float*)d_out;

  const size_t nX   = (size_t)MROWS * DIMX;   //  8,388,608
  const size_t nW1f = (size_t)CQKV  * DIMX;   // 12,582,912
  const size_t nW2f = (size_t)DIMX  * 1024;   //  4,194,304
  const size_t nQKV = (size_t)MROWS * CQKV;   //  6,291,456
  const size_t nATT = (size_t)MROWS * 1024;   //  2,097,152

  half_t* ws   = (half_t*)d_ws;
  half_t* xh   = ws;
  half_t* w1f  = xh   + nX;
  half_t* w2f  = w1f  + nW1f;
  half_t* qkvc = w2f  + nW2f;
  half_t* attc = qkvc + nQKV;
  float*  b1f  = (float*)(attc + nATT);       // 3072 floats
  // split-K partials: C0 reuses d_out (2048*4096 f32 >= 2048*3072 f32,
  // fully overwritten by GEMM2 at the end); C1 in workspace tail.
  float*  c1   = (float*)(b1f + 4096);        // 16B-aligned; 25.2 MB
  // V^T [2][1024][1024] f16 (4 MB) overlays xh — dead after GEMM1.
  half_t* vt   = xh;

  cvt_f32_f16_kernel<<<4096, 256, 0, stream>>>((const float4*)x, (f16x4*)xh,
                                               (int)(nX / 4));
  fold_w1_kernel<<<12288, 256, 0, stream>>>(W1, b1, w1f, b1f);
  fold_w2_kernel<<<4096, 256, 0, stream>>>(W2, w2f);

  // GEMM1: split-K=2 -> 768 blocks (3/CU) of 128x128x2048 partials
  gemm_nt_splitk<<<dim3(CQKV / 128, MROWS / 128, 2), 256, 0, stream>>>(
      xh, w1f, out /*C0*/, c1 /*C1*/, MROWS, CQKV, DIMX);
  splitk_reduce_kernel<<<dim3(CQKV / 4 / 256, MROWS), 256, 0, stream>>>(
      (const float4*)out, (const float4*)c1, (const float4*)b1f,
      (f16x4*)qkvc);

  v_transpose_kernel<<<dim3(16, 16, BB), 256, 0, stream>>>(qkvc, vt);

  attn_kernel<<<dim3(16, BB * NH), 256, 0, stream>>>(qkvc, vt, attc);

  gemm_nt_bias<0><<<dim3(DIMX / 128, MROWS / 128), 256, 0, stream>>>(
      attc, w2f, b2, (void*)out, MROWS, DIMX, 1024);
}

// Round 5
// 350.156 us; speedup vs baseline: 1.0055x; 1.0055x over previous
//
#include <hip/hip_runtime.h>

// ---------------- problem constants ----------------
#define DIMX  4096
#define NH    32
#define HD    128
#define BB    2
#define TT    1024
#define MROWS (BB*TT)          // 2048
#define CQKV  3072             // compact qkv cols: 1024 q_red | 1024 k | 1024 v
// (1/sqrt(128)) * log2(e): lets attention use exp2 directly
#define SCALE_Q 0.12751743f

typedef _Float16 half_t;
typedef __attribute__((ext_vector_type(4))) _Float16 f16x4;
typedef __attribute__((ext_vector_type(8))) _Float16 f16x8;
typedef __attribute__((ext_vector_type(4))) float    f32x4;

// async global->LDS, 16B/lane; LDS dest = wave-uniform base + lane*16
__device__ __forceinline__ void async_copy16(const void* gsrc, void* ldst) {
  __builtin_amdgcn_global_load_lds(
      (const __attribute__((address_space(1))) unsigned int*)gsrc,
      (__attribute__((address_space(3))) unsigned int*)ldst,
      16, 0, 0);
}

// ---------------- fp32 -> fp16 conversion ----------------
__global__ __launch_bounds__(256) void cvt_f32_f16_kernel(
    const float4* __restrict__ src, f16x4* __restrict__ dst, int n4) {
  int stride = gridDim.x * blockDim.x;
  for (int i = blockIdx.x * blockDim.x + threadIdx.x; i < n4; i += stride) {
    float4 f = src[i];
    f16x4 h;
    h.x = (_Float16)f.x; h.y = (_Float16)f.y;
    h.z = (_Float16)f.z; h.w = (_Float16)f.w;
    dst[i] = h;
  }
}

// ---------------- fold W1 -> W1f [3072][4096] fp16, b1f [3072] f32 ----------
// rows 0..1023:  q_red rows = (sum of 4 q rows) * SCALE_Q
// rows 1024..3071: k/v rows copied (W1 row = row + 3072)
__global__ __launch_bounds__(256) void fold_w1_kernel(
    const float* __restrict__ W1, const float* __restrict__ b1,
    half_t* __restrict__ W1f, float* __restrict__ b1f)
{
  long idx = (long)blockIdx.x * 256 + threadIdx.x;   // 3072*1024
  int row = (int)(idx >> 10);
  int c4  = ((int)idx & 1023) << 2;
  f16x4 h;
  if (row < 1024) {
    const float* s = W1 + ((long)row << 2) * DIMX + c4;
    float4 a = *(const float4*)s;
    float4 b = *(const float4*)(s + DIMX);
    float4 c = *(const float4*)(s + 2 * DIMX);
    float4 d = *(const float4*)(s + 3 * DIMX);
    h.x = (_Float16)((a.x + b.x + c.x + d.x) * SCALE_Q);
    h.y = (_Float16)((a.y + b.y + c.y + d.y) * SCALE_Q);
    h.z = (_Float16)((a.z + b.z + c.z + d.z) * SCALE_Q);
    h.w = (_Float16)((a.w + b.w + c.w + d.w) * SCALE_Q);
    if (c4 == 0) {
      const float* bb = b1 + ((long)row << 2);
      b1f[row] = (bb[0] + bb[1] + bb[2] + bb[3]) * SCALE_Q;
    }
  } else {
    const float* s = W1 + ((long)(row + 3072)) * DIMX + c4;
    float4 a = *(const float4*)s;
    h.x = (_Float16)a.x; h.y = (_Float16)a.y;
    h.z = (_Float16)a.z; h.w = (_Float16)a.w;
    if (c4 == 0) b1f[row] = b1[row + 3072];
  }
  *(f16x4*)&W1f[(long)row * DIMX + c4] = h;
}

// ---------------- fold W2 -> W2f [4096][1024] fp16 ----------------
// W2f[n][j] = sum_{r<4} W2[n][4j+r]
__global__ __launch_bounds__(256) void fold_w2_kernel(
    const float* __restrict__ W2, half_t* __restrict__ W2f)
{
  long idx = (long)blockIdx.x * 256 + threadIdx.x;   // 4096*256
  int row = (int)(idx >> 8);
  int j4  = ((int)idx & 255) << 2;
  const float* s = W2 + (long)row * DIMX + ((long)j4 << 2);
  float4 a = *(const float4*)s;
  float4 b = *(const float4*)(s + 4);
  float4 c = *(const float4*)(s + 8);
  float4 d = *(const float4*)(s + 12);
  f16x4 h;
  h.x = (_Float16)(a.x + a.y + a.z + a.w);
  h.y = (_Float16)(b.x + b.y + b.z + b.w);
  h.z = (_Float16)(c.x + c.y + c.z + c.w);
  h.w = (_Float16)(d.x + d.y + d.z + d.w);
  *(f16x4*)&W2f[(long)row * 1024 + j4] = h;
}

// ============================================================================
// NT GEMM core, BK=64 + XOR chunk swizzle (T2, both-sides: rule #21).
// Tile 128x128, 4 waves 2x2, each wave 64x64 = 4x4 mfma_16x16x32 per kk.
// R3 verified: SQ_LDS_BANK_CONFLICT = 0, 810 TF (~90% of 2-barrier ceiling).
// R5: + XCD-aware block swizzle (T1) for L2 locality.
// ============================================================================

// ---------------- split-K NT GEMM (GEMM1): 2 K-slices, f32 partials --------
// grid (N/128, M/128, 2) = 768 blocks = 3/CU.  768%8==0 -> chunked XCD
// swizzle is bijective: XCD k owns 96 contiguous tiles (4 M-rows x 24 N-cols
// per K-slice quarter) -> A-panel reuse lands in the XCD's private L2.
__global__ __launch_bounds__(256, 3) void gemm_nt_splitk(
    const half_t* __restrict__ A, const half_t* __restrict__ Bw,
    float* __restrict__ Cp0, float* __restrict__ Cp1,
    int M, int N, int K)
{
  __shared__ alignas(16) half_t As[128 * 64];   // 16 KB
  __shared__ alignas(16) half_t Bs[128 * 64];   // 16 KB

  const int tid  = threadIdx.x;
  const int lane = tid & 63;
  const int w    = tid >> 6;

  // XCD swizzle: flat dispatch id -> contiguous tile chunk per XCD
  const int GX = gridDim.x, GY = gridDim.y;
  const int total = GX * GY * gridDim.z;
  const int flat  = blockIdx.x + GX * (blockIdx.y + GY * blockIdx.z);
  const int swz   = (flat & 7) * (total >> 3) + (flat >> 3);
  const int bx = swz % GX;
  const int by = (swz / GX) % GY;
  const int bz = swz / (GX * GY);

  const long row0 = (long)by * 128;
  const long col0 = (long)bx * 128;
  const int  KH   = K >> 1;
  const long k0   = (long)bz * KH;

  // staging: thread t -> rows {i*32 + (t>>3)}, source chunk (t&7)^(row&7)
  const int rr = tid >> 3;                       // 0..31
  const int cs = (((tid & 7) ^ (rr & 7)) << 3);  // swizzled col (halves)
  const half_t* ga[4]; const half_t* gb[4];
#pragma unroll
  for (int i = 0; i < 4; ++i) {
    ga[i] = A  + (row0 + i * 32 + rr) * K + k0 + cs;
    gb[i] = Bw + (col0 + i * 32 + rr) * K + k0 + cs;
  }
  half_t* lds_a = &As[w * 512];   // + i*2048; HW adds lane*16B (linear) ✓
  half_t* lds_b = &Bs[w * 512];

  // wave 2x2: wave w owns C[wm..wm+63][wn..wn+63]
  const int wm = (w >> 1) * 64;
  const int wn = (w & 1) * 64;
  const int fr   = lane & 15;
  const int quad = lane >> 4;
  const int rsw  = fr & 7;
  const int o0 = ((quad ^ rsw) << 3);            // kk=0  chunk (halves)
  const int o1 = (((quad | 4) ^ rsw) << 3);      // kk=32 chunk
  const half_t* paw = &As[(wm + fr) * 64];
  const half_t* pbw = &Bs[(wn + fr) * 64];

  f32x4 acc[4][4] = {};

  for (int kt = 0; kt < KH; kt += 64) {
    __syncthreads();
#pragma unroll
    for (int i = 0; i < 4; ++i) async_copy16(ga[i] + kt, lds_a + i * 2048);
#pragma unroll
    for (int i = 0; i < 4; ++i) async_copy16(gb[i] + kt, lds_b + i * 2048);
    __syncthreads();   // compiler drains vmcnt(0) before s_barrier

    f16x8 af[4], bf[4];
#pragma unroll
    for (int mi = 0; mi < 4; ++mi) af[mi] = *(const f16x8*)(paw + mi * 1024 + o0);
#pragma unroll
    for (int ni = 0; ni < 4; ++ni) bf[ni] = *(const f16x8*)(pbw + ni * 1024 + o0);
#pragma unroll
    for (int mi = 0; mi < 4; ++mi)
#pragma unroll
      for (int ni = 0; ni < 4; ++ni)
        acc[mi][ni] = __builtin_amdgcn_mfma_f32_16x16x32_f16(
            af[mi], bf[ni], acc[mi][ni], 0, 0, 0);

#pragma unroll
    for (int mi = 0; mi < 4; ++mi) af[mi] = *(const f16x8*)(paw + mi * 1024 + o1);
#pragma unroll
    for (int ni = 0; ni < 4; ++ni) bf[ni] = *(const f16x8*)(pbw + ni * 1024 + o1);
#pragma unroll
    for (int mi = 0; mi < 4; ++mi)
#pragma unroll
      for (int ni = 0; ni < 4; ++ni)
        acc[mi][ni] = __builtin_amdgcn_mfma_f32_16x16x32_f16(
            af[mi], bf[ni], acc[mi][ni], 0, 0, 0);
  }

  float* Cp = bz ? Cp1 : Cp0;
  // C/D layout: col = lane&15, row = (lane>>4)*4 + r
  const int er = (lane >> 4) * 4;
  const int ec = lane & 15;
#pragma unroll
  for (int mi = 0; mi < 4; ++mi) {
#pragma unroll
    for (int ni = 0; ni < 4; ++ni) {
      long gn = col0 + wn + ni * 16 + ec;
#pragma unroll
      for (int r = 0; r < 4; ++r) {
        long gm = row0 + wm + mi * 16 + er + r;
        Cp[gm * N + gn] = acc[mi][ni][r];
      }
    }
  }
}

// ---------------- plain NT GEMM + bias (GEMM2) -----------------------------
// Same BK=64 swizzled body; grid (32, 16) = 512 blocks (even 2/CU).
// XCD rect swizzle: XCD k owns an 8x8 tile rectangle -> A-rows 2MB + B-cols
// 2MB both fit the 4MB XCD L2 (vs touching ALL panels under round-robin).
template<int OUT_IS_F16>
__global__ __launch_bounds__(256, 3) void gemm_nt_bias(
    const half_t* __restrict__ A, const half_t* __restrict__ Bw,
    const float* __restrict__ bias, void* __restrict__ Cout,
    int M, int N, int K)
{
  __shared__ alignas(16) half_t As[128 * 64];   // 16 KB
  __shared__ alignas(16) half_t Bs[128 * 64];   // 16 KB

  const int tid  = threadIdx.x;
  const int lane = tid & 63;
  const int w    = tid >> 6;

  // rect swizzle (GX%4==0, GY%2==0): xcd k -> rect (k&3)*GX/4 x (k>>2)*GY/2
  const int GX = gridDim.x, GY = gridDim.y;
  const int GXq = GX >> 2, GYh = GY >> 1;
  const int flat = blockIdx.x + GX * blockIdx.y;
  const int k8   = flat & 7;
  const int i8   = flat >> 3;
  const int bx = (k8 & 3) * GXq + (i8 % GXq);
  const int by = (k8 >> 2) * GYh + (i8 / GXq);

  const long row0 = (long)by * 128;
  const long col0 = (long)bx * 128;

  const int rr = tid >> 3;
  const int cs = (((tid & 7) ^ (rr & 7)) << 3);
  const half_t* ga[4]; const half_t* gb[4];
#pragma unroll
  for (int i = 0; i < 4; ++i) {
    ga[i] = A  + (row0 + i * 32 + rr) * K + cs;
    gb[i] = Bw + (col0 + i * 32 + rr) * K + cs;
  }
  half_t* lds_a = &As[w * 512];
  half_t* lds_b = &Bs[w * 512];

  const int wm = (w >> 1) * 64;
  const int wn = (w & 1) * 64;
  const int fr   = lane & 15;
  const int quad = lane >> 4;
  const int rsw  = fr & 7;
  const int o0 = ((quad ^ rsw) << 3);
  const int o1 = (((quad | 4) ^ rsw) << 3);
  const half_t* paw = &As[(wm + fr) * 64];
  const half_t* pbw = &Bs[(wn + fr) * 64];

  f32x4 acc[4][4] = {};

  for (int kt = 0; kt < K; kt += 64) {
    __syncthreads();
#pragma unroll
    for (int i = 0; i < 4; ++i) async_copy16(ga[i] + kt, lds_a + i * 2048);
#pragma unroll
    for (int i = 0; i < 4; ++i) async_copy16(gb[i] + kt, lds_b + i * 2048);
    __syncthreads();

    f16x8 af[4], bf[4];
#pragma unroll
    for (int mi = 0; mi < 4; ++mi) af[mi] = *(const f16x8*)(paw + mi * 1024 + o0);
#pragma unroll
    for (int ni = 0; ni < 4; ++ni) bf[ni] = *(const f16x8*)(pbw + ni * 1024 + o0);
#pragma unroll
    for (int mi = 0; mi < 4; ++mi)
#pragma unroll
      for (int ni = 0; ni < 4; ++ni)
        acc[mi][ni] = __builtin_amdgcn_mfma_f32_16x16x32_f16(
            af[mi], bf[ni], acc[mi][ni], 0, 0, 0);

#pragma unroll
    for (int mi = 0; mi < 4; ++mi) af[mi] = *(const f16x8*)(paw + mi * 1024 + o1);
#pragma unroll
    for (int ni = 0; ni < 4; ++ni) bf[ni] = *(const f16x8*)(pbw + ni * 1024 + o1);
#pragma unroll
    for (int mi = 0; mi < 4; ++mi)
#pragma unroll
      for (int ni = 0; ni < 4; ++ni)
        acc[mi][ni] = __builtin_amdgcn_mfma_f32_16x16x32_f16(
            af[mi], bf[ni], acc[mi][ni], 0, 0, 0);
  }

  const int er = (lane >> 4) * 4;
  const int ec = lane & 15;
#pragma unroll
  for (int mi = 0; mi < 4; ++mi) {
#pragma unroll
    for (int ni = 0; ni < 4; ++ni) {
      long gn = col0 + wn + ni * 16 + ec;
      float bv = bias[gn];
#pragma unroll
      for (int r = 0; r < 4; ++r) {
        long gm = row0 + wm + mi * 16 + er + r;
        float v = acc[mi][ni][r] + bv;
        if (OUT_IS_F16) ((half_t*)Cout)[gm * N + gn] = (half_t)v;
        else            ((float*)Cout)[gm * N + gn]  = v;
      }
    }
  }
}

// ---------------- split-K reduce (Q,K cols only): qkvc = f16(C0+C1+bias) ---
// grid (2, 2048); one float4 per thread; partials are L3-hot.
__global__ __launch_bounds__(256) void splitk_reduce_kernel(
    const float4* __restrict__ C0, const float4* __restrict__ C1,
    const float4* __restrict__ bias4, f16x4* __restrict__ dst)
{
  const int col  = blockIdx.x * 256 + threadIdx.x;   // 0..511 (2048 cols /4)
  const long row = blockIdx.y;                       // 0..2047
  const long i   = row * (CQKV / 4) + col;
  float4 a = C0[i];
  float4 b = C1[i];
  float4 bv = bias4[col];
  f16x4 h;
  h.x = (_Float16)(a.x + b.x + bv.x);
  h.y = (_Float16)(a.y + b.y + bv.y);
  h.z = (_Float16)(a.z + b.z + bv.z);
  h.w = (_Float16)(a.w + b.w + bv.w);
  dst[i] = h;
}

// ---------- fused V reduce+transpose: vt[b][d][tok] = f16(C0+C1+bias) ------
// Replaces {reduce of v-cols + separate v_transpose}: reads f32 partials
// (L3-hot), adds bias, LDS 64x64 transpose, writes vt directly.
__global__ __launch_bounds__(256) void v_reduce_transpose_kernel(
    const float* __restrict__ C0, const float* __restrict__ C1,
    const float* __restrict__ bias, half_t* __restrict__ vt)
{
  __shared__ half_t lt[64][72];
  const int t  = threadIdx.x;
  const int b  = blockIdx.z;
  const int d0 = blockIdx.x * 64;      // dim tile (0..1023)
  const int k0 = blockIdx.y * 64;      // token tile (within batch)
  const int tl = t >> 3;               // 0..31
  const int dc = (t & 7) * 8;          // 0..56

  const long base0 = ((long)b * TT + k0 + tl) * CQKV + 2048 + d0 + dc;
  float4 bv0 = *(const float4*)(bias + 2048 + d0 + dc);
  float4 bv1 = *(const float4*)(bias + 2048 + d0 + dc + 4);
#pragma unroll
  for (int half = 0; half < 2; ++half) {
    const long base = base0 + (long)half * 32 * CQKV;
    float4 a0 = *(const float4*)(C0 + base);
    float4 a1 = *(const float4*)(C0 + base + 4);
    float4 c0 = *(const float4*)(C1 + base);
    float4 c1 = *(const float4*)(C1 + base + 4);
    f16x8 hvec;
    hvec[0] = (_Float16)(a0.x + c0.x + bv0.x);
    hvec[1] = (_Float16)(a0.y + c0.y + bv0.y);
    hvec[2] = (_Float16)(a0.z + c0.z + bv0.z);
    hvec[3] = (_Float16)(a0.w + c0.w + bv0.w);
    hvec[4] = (_Float16)(a1.x + c1.x + bv1.x);
    hvec[5] = (_Float16)(a1.y + c1.y + bv1.y);
    hvec[6] = (_Float16)(a1.z + c1.z + bv1.z);
    hvec[7] = (_Float16)(a1.w + c1.w + bv1.w);
    *(f16x8*)&lt[tl + half * 32][dc] = hvec;
  }
  __syncthreads();

  // lt[a][b] = V[k0+a][d0+b]; write vt[d0+tl][k0+dc+j] = lt[dc+j][tl]
  half_t* dstp = vt + ((long)b * 1024 + d0 + tl) * 1024 + k0 + dc;
  f16x8 o0, o1;
#pragma unroll
  for (int j = 0; j < 8; ++j) {
    o0[j] = lt[dc + j][tl];
    o1[j] = lt[dc + j][tl + 32];
  }
  *(f16x8*)dstp = o0;
  *(f16x8*)(dstp + 32 * 1024) = o1;
}

// ---------------- MFMA flash attention (compact 32-dim heads) --------------
// Block: 256 thr = 4 waves; wave w owns 16 queries. Grid (16, B*NH).
// R5: UNCAPPED launch bounds (the old (256,4) forced <=64 VGPR -> spills in
// the per-chunk loop). XCD swizzle: XCD k owns heads [8k,8k+8) -> K/V 1MB
// stays L2-resident per XCD.
// Per 64-key chunk: K and V staged with ONE async_copy16 each into
// XOR-swizzled packed LDS (rule #21: linear dest + swizzled SOURCE +
// matching swizzled read). l[q] via all-ones A-fragment MFMA.
#define PSS 72
__global__ __launch_bounds__(256) void attn_kernel(
    const half_t* __restrict__ qkv,  // [MROWS][3072] (cols 2048.. unused)
    const half_t* __restrict__ vt,   // [BB][1024 d][1024 tok]
    half_t* __restrict__ attc)       // [MROWS][1024]
{
  __shared__ alignas(16) half_t Ks[32 * 64];        // 4 KB
  __shared__ alignas(16) half_t Vs[32 * 64];        // 4 KB
  __shared__ alignas(16) half_t Ps[4][16 * PSS];    // per-wave [q][key]

  const int tid  = threadIdx.x;
  const int lane = tid & 63;
  const int w    = tid >> 6;
  const int low  = lane & 15;
  const int quad = lane >> 4;

  // XCD swizzle: flat -> (tile, bh) with heads chunked per XCD
  const int flat = blockIdx.x + 16 * blockIdx.y;   // 0..1023
  const int swz  = (flat & 7) * 128 + (flat >> 3);
  const int tile = swz & 15;
  const int bh   = swz >> 4;
  const int b    = bh >> 5;
  const int h    = bh & 31;
  const long rb  = (long)b * TT;

  // staging source addresses (per thread); LDS dest linear: t -> t*16B
  const int su  = tid >> 3;              // LDS row (K: u=key>>1, V: d)
  const int sp  = tid & 7;               // stored chunk position
  const int spx = sp ^ (su & 7);         // source chunk
  // K: key = 2u + (spx>>2), d-chunk = spx&3
  const half_t* kg = qkv + (rb + 2 * su + (spx >> 2)) * CQKV + 1024
                         + h * 32 + (spx & 3) * 8;
  // V: vt row d = h*32 + su, key offset spx*8
  const half_t* vg = vt + ((long)b * 1024 + h * 32 + su) * 1024 + spx * 8;
  half_t* kdst = &Ks[w * 512];           // wave-uniform; HW adds lane*16B
  half_t* vdst = &Vs[w * 512];
  half_t* psw  = &Ps[w][0];
  float*  Ob   = (float*)psw;            // epilogue overlay [q][36 floats]

  const int t0   = tile * 64;
  const int qg   = t0 + 16 * w;

  // Q fragment: A[m=low][k=quad*8+j]
  f16x8 qf = *(const f16x8*)&qkv[(rb + qg + low) * CQKV + h * 32 + quad * 8];

  // all-ones A-fragment: D[m][n] = sum_k P[n][k] = l[n] for every m
  f16x8 onesf;
#pragma unroll
  for (int i = 0; i < 8; ++i) onesf[i] = (_Float16)1.0f;

  f32x4 acc0 = {}, acc1 = {}, acc2 = {};
  const f32x4 zero = {};

  const int dsw = low & 7;
  const int ksw = (low >> 1) & 7;
  const int kp  = (((low & 1) << 2) | quad) ^ ksw;   // Ks read chunk pos

  for (int c = 0; c <= t0; c += 64) {
    __syncthreads();
    async_copy16(kg + (long)c * CQKV, kdst);
    async_copy16(vg + c, vdst);
    __syncthreads();

    // S = Q.K^T : C[m=q][n=key]
    f32x4 s[4];
#pragma unroll
    for (int st = 0; st < 4; ++st) {
      const int u = st * 8 + (low >> 1);
      f16x8 kf = *(const f16x8*)&Ks[u * 64 + kp * 8];
      s[st] = __builtin_amdgcn_mfma_f32_16x16x32_f16(qf, kf, zero, 0, 0, 0);
    }

    // P = exp2(S) (causal mask only at diagonal chunk), write to LDS
    const bool diag = (c == t0);
#pragma unroll
    for (int st = 0; st < 4; ++st) {
#pragma unroll
      for (int r = 0; r < 4; ++r) {
        const int key = c + st * 16 + low;
        const int q   = qg + 4 * quad + r;
        float p = __builtin_amdgcn_exp2f(s[st][r]);
        if (diag && key > q) p = 0.f;
        psw[(4 * quad + r) * PSS + st * 16 + low] = (_Float16)p;
      }
    }

    // P frags (B: [n=q][k=key])
    f16x8 p0 = *(const f16x8*)&psw[low * PSS + 0 * 32 + quad * 8];
    f16x8 p1 = *(const f16x8*)&psw[low * PSS + 1 * 32 + quad * 8];

    // Vs frags (A: [m=d][k=key]), swizzled chunk reads
    f16x8 v00 = *(const f16x8*)&Vs[(0  + low) * 64 + ((0 + quad) ^ dsw) * 8];
    f16x8 v01 = *(const f16x8*)&Vs[(0  + low) * 64 + ((4 + quad) ^ dsw) * 8];
    f16x8 v10 = *(const f16x8*)&Vs[(16 + low) * 64 + ((0 + quad) ^ dsw) * 8];
    f16x8 v11 = *(const f16x8*)&Vs[(16 + low) * 64 + ((4 + quad) ^ dsw) * 8];

    acc0 = __builtin_amdgcn_mfma_f32_16x16x32_f16(v00,   p0, acc0, 0, 0, 0);
    acc0 = __builtin_amdgcn_mfma_f32_16x16x32_f16(v01,   p1, acc0, 0, 0, 0);
    acc1 = __builtin_amdgcn_mfma_f32_16x16x32_f16(v10,   p0, acc1, 0, 0, 0);
    acc1 = __builtin_amdgcn_mfma_f32_16x16x32_f16(v11,   p1, acc1, 0, 0, 0);
    acc2 = __builtin_amdgcn_mfma_f32_16x16x32_f16(onesf, p0, acc2, 0, 0, 0);
    acc2 = __builtin_amdgcn_mfma_f32_16x16x32_f16(onesf, p1, acc2, 0, 0, 0);
  }

  // ---- epilogue ----
  __syncthreads();   // last chunk's Ps reads done before Ob overlay writes

  // every lane's acc2[r] = l[q = lane&15]
  float linv = 1.0f / acc2[0];

  // O^T[d=16t+4quad+r][q=low] -> Ob[q][d], scaled
#pragma unroll
  for (int r = 0; r < 4; ++r) {
    Ob[low * 36 + 0  + 4 * quad + r] = acc0[r] * linv;
    Ob[low * 36 + 16 + 4 * quad + r] = acc1[r] * linv;
  }
  __syncthreads();

  // row-wise readback: lane (q=low, dblk=quad) -> 8 contiguous dims
  f16x8 ov;
#pragma unroll
  for (int i = 0; i < 8; ++i)
    ov[i] = (_Float16)Ob[low * 36 + quad * 8 + i];
  *(f16x8*)&attc[(rb + qg + low) * 1024 + h * 32 + quad * 8] = ov;
}

// ---------------- launcher ----------------
extern "C" void kernel_launch(void* const* d_in, const int* in_sizes, int n_in,
                              void* d_out, int out_size, void* d_ws, size_t ws_size,
                              hipStream_t stream) {
  (void)in_sizes; (void)n_in; (void)out_size; (void)ws_size;
  const float* x  = (const float*)d_in[0];
  const float* W1 = (const float*)d_in[1];
  const float* b1 = (const float*)d_in[2];
  const float* W2 = (const float*)d_in[3];
  const float* b2 = (const float*)d_in[4];
  float* out = (float*)d_out;

  const size_t nX   = (size_t)MROWS * DIMX;   //  8,388,608
  const size_t nW1f = (size_t)CQKV  * DIMX;   // 12,582,912
  const size_t nW2f = (size_t)DIMX  * 1024;   //  4,194,304
  const size_t nQKV = (size_t)MROWS * CQKV;   //  6,291,456
  const size_t nATT = (size_t)MROWS * 1024;   //  2,097,152

  half_t* ws   = (half_t*)d_ws;
  half_t* xh   = ws;
  half_t* w1f  = xh   + nX;
  half_t* w2f  = w1f  + nW1f;
  half_t* qkvc = w2f  + nW2f;
  half_t* attc = qkvc + nQKV;
  float*  b1f  = (float*)(attc + nATT);       // 3072 floats
  // split-K partials: C0 reuses d_out (2048*4096 f32 >= 2048*3072 f32,
  // fully overwritten by GEMM2 at the end); C1 in workspace tail.
  float*  c1   = (float*)(b1f + 4096);        // 16B-aligned; 25.2 MB
  // V^T [2][1024][1024] f16 (4 MB) overlays xh — dead after GEMM1.
  half_t* vt   = xh;

  cvt_f32_f16_kernel<<<4096, 256, 0, stream>>>((const float4*)x, (f16x4*)xh,
                                               (int)(nX / 4));
  fold_w1_kernel<<<12288, 256, 0, stream>>>(W1, b1, w1f, b1f);
  fold_w2_kernel<<<4096, 256, 0, stream>>>(W2, w2f);

  // GEMM1: split-K=2 -> 768 blocks (3/CU) of 128x128x2048 partials
  gemm_nt_splitk<<<dim3(CQKV / 128, MROWS / 128, 2), 256, 0, stream>>>(
      xh, w1f, out /*C0*/, c1 /*C1*/, MROWS, CQKV, DIMX);

  // Q,K cols -> qkvc; V cols -> vt (fused reduce+transpose)
  splitk_reduce_kernel<<<dim3(2, MROWS), 256, 0, stream>>>(
      (const float4*)out, (const float4*)c1, (const float4*)b1f,
      (f16x4*)qkvc);
  v_reduce_transpose_kernel<<<dim3(16, 16, BB), 256, 0, stream>>>(
      out, c1, b1f, vt);

  attn_kernel<<<dim3(16, BB * NH), 256, 0, stream>>>(qkvc, vt, attc);

  gemm_nt_bias<0><<<dim3(DIMX / 128, MROWS / 128), 256, 0, stream>>>(
      attc, w2f, b2, (void*)out, MROWS, DIMX, 1024);
}

// Round 6
// 349.439 us; speedup vs baseline: 1.0075x; 1.0021x over previous
//
#include <hip/hip_runtime.h>

// ---------------- problem constants ----------------
#define DIMX  4096
#define NH    32
#define HD    128
#define BB    2
#define TT    1024
#define MROWS (BB*TT)          // 2048
#define CQKV  3072             // compact qkv cols: 1024 q_red | 1024 k | 1024 v
// (1/sqrt(128)) * log2(e): lets attention use exp2 directly
#define SCALE_Q 0.12751743f

typedef _Float16 half_t;
typedef __attribute__((ext_vector_type(4))) _Float16 f16x4;
typedef __attribute__((ext_vector_type(8))) _Float16 f16x8;
typedef __attribute__((ext_vector_type(4))) float    f32x4;

// async global->LDS, 16B/lane; LDS dest = wave-uniform base + lane*16
__device__ __forceinline__ void async_copy16(const void* gsrc, void* ldst) {
  __builtin_amdgcn_global_load_lds(
      (const __attribute__((address_space(1))) unsigned int*)gsrc,
      (__attribute__((address_space(3))) unsigned int*)ldst,
      16, 0, 0);
}

// ---------------- fp32 -> fp16 conversion ----------------
__global__ __launch_bounds__(256) void cvt_f32_f16_kernel(
    const float4* __restrict__ src, f16x4* __restrict__ dst, int n4) {
  int stride = gridDim.x * blockDim.x;
  for (int i = blockIdx.x * blockDim.x + threadIdx.x; i < n4; i += stride) {
    float4 f = src[i];
    f16x4 h;
    h.x = (_Float16)f.x; h.y = (_Float16)f.y;
    h.z = (_Float16)f.z; h.w = (_Float16)f.w;
    dst[i] = h;
  }
}

// ---------------- fold W1 -> W1f [3072][4096] fp16, b1f [3072] f32 ----------
// rows 0..1023:  q_red rows = (sum of 4 q rows) * SCALE_Q
// rows 1024..3071: k/v rows copied (W1 row = row + 3072)
__global__ __launch_bounds__(256) void fold_w1_kernel(
    const float* __restrict__ W1, const float* __restrict__ b1,
    half_t* __restrict__ W1f, float* __restrict__ b1f)
{
  long idx = (long)blockIdx.x * 256 + threadIdx.x;   // 3072*1024
  int row = (int)(idx >> 10);
  int c4  = ((int)idx & 1023) << 2;
  f16x4 h;
  if (row < 1024) {
    const float* s = W1 + ((long)row << 2) * DIMX + c4;
    float4 a = *(const float4*)s;
    float4 b = *(const float4*)(s + DIMX);
    float4 c = *(const float4*)(s + 2 * DIMX);
    float4 d = *(const float4*)(s + 3 * DIMX);
    h.x = (_Float16)((a.x + b.x + c.x + d.x) * SCALE_Q);
    h.y = (_Float16)((a.y + b.y + c.y + d.y) * SCALE_Q);
    h.z = (_Float16)((a.z + b.z + c.z + d.z) * SCALE_Q);
    h.w = (_Float16)((a.w + b.w + c.w + d.w) * SCALE_Q);
    if (c4 == 0) {
      const float* bb = b1 + ((long)row << 2);
      b1f[row] = (bb[0] + bb[1] + bb[2] + bb[3]) * SCALE_Q;
    }
  } else {
    const float* s = W1 + ((long)(row + 3072)) * DIMX + c4;
    float4 a = *(const float4*)s;
    h.x = (_Float16)a.x; h.y = (_Float16)a.y;
    h.z = (_Float16)a.z; h.w = (_Float16)a.w;
    if (c4 == 0) b1f[row] = b1[row + 3072];
  }
  *(f16x4*)&W1f[(long)row * DIMX + c4] = h;
}

// ---------------- fold W2 -> W2f [4096][1024] fp16 ----------------
// W2f[n][j] = sum_{r<4} W2[n][4j+r]
__global__ __launch_bounds__(256) void fold_w2_kernel(
    const float* __restrict__ W2, half_t* __restrict__ W2f)
{
  long idx = (long)blockIdx.x * 256 + threadIdx.x;   // 4096*256
  int row = (int)(idx >> 8);
  int j4  = ((int)idx & 255) << 2;
  const float* s = W2 + (long)row * DIMX + ((long)j4 << 2);
  float4 a = *(const float4*)s;
  float4 b = *(const float4*)(s + 4);
  float4 c = *(const float4*)(s + 8);
  float4 d = *(const float4*)(s + 12);
  f16x4 h;
  h.x = (_Float16)(a.x + a.y + a.z + a.w);
  h.y = (_Float16)(b.x + b.y + b.z + b.w);
  h.z = (_Float16)(c.x + c.y + c.z + c.w);
  h.w = (_Float16)(d.x + d.y + d.z + d.w);
  *(f16x4*)&W2f[(long)row * 1024 + j4] = h;
}

// ============================================================================
// NT GEMM core, BK=64 + XOR chunk swizzle (T2, both-sides: rule #21).
// Tile 128x128, 4 waves 2x2, each wave 64x64 = 4x4 mfma_16x16x32 per kk.
// R3 verified: SQ_LDS_BANK_CONFLICT = 0, 810 TF (~90% of 2-barrier ceiling).
// R5: + XCD-aware block swizzle (T1): FETCH 81->68.6 MB.
// ============================================================================

// ---------------- split-K NT GEMM (GEMM1): 2 K-slices, f32 partials --------
// grid (N/128, M/128, 2) = 768 blocks = 3/CU.
__global__ __launch_bounds__(256, 3) void gemm_nt_splitk(
    const half_t* __restrict__ A, const half_t* __restrict__ Bw,
    float* __restrict__ Cp0, float* __restrict__ Cp1,
    int M, int N, int K)
{
  __shared__ alignas(16) half_t As[128 * 64];   // 16 KB
  __shared__ alignas(16) half_t Bs[128 * 64];   // 16 KB

  const int tid  = threadIdx.x;
  const int lane = tid & 63;
  const int w    = tid >> 6;

  // XCD swizzle: flat dispatch id -> contiguous tile chunk per XCD
  const int GX = gridDim.x, GY = gridDim.y;
  const int total = GX * GY * gridDim.z;
  const int flat  = blockIdx.x + GX * (blockIdx.y + GY * blockIdx.z);
  const int swz   = (flat & 7) * (total >> 3) + (flat >> 3);
  const int bx = swz % GX;
  const int by = (swz / GX) % GY;
  const int bz = swz / (GX * GY);

  const long row0 = (long)by * 128;
  const long col0 = (long)bx * 128;
  const int  KH   = K >> 1;
  const long k0   = (long)bz * KH;

  // staging: thread t -> rows {i*32 + (t>>3)}, source chunk (t&7)^(row&7)
  const int rr = tid >> 3;                       // 0..31
  const int cs = (((tid & 7) ^ (rr & 7)) << 3);  // swizzled col (halves)
  const half_t* ga[4]; const half_t* gb[4];
#pragma unroll
  for (int i = 0; i < 4; ++i) {
    ga[i] = A  + (row0 + i * 32 + rr) * K + k0 + cs;
    gb[i] = Bw + (col0 + i * 32 + rr) * K + k0 + cs;
  }
  half_t* lds_a = &As[w * 512];   // + i*2048; HW adds lane*16B (linear) ✓
  half_t* lds_b = &Bs[w * 512];

  // wave 2x2: wave w owns C[wm..wm+63][wn..wn+63]
  const int wm = (w >> 1) * 64;
  const int wn = (w & 1) * 64;
  const int fr   = lane & 15;
  const int quad = lane >> 4;
  const int rsw  = fr & 7;
  const int o0 = ((quad ^ rsw) << 3);            // kk=0  chunk (halves)
  const int o1 = (((quad | 4) ^ rsw) << 3);      // kk=32 chunk
  const half_t* paw = &As[(wm + fr) * 64];
  const half_t* pbw = &Bs[(wn + fr) * 64];

  f32x4 acc[4][4] = {};

  for (int kt = 0; kt < KH; kt += 64) {
    __syncthreads();
#pragma unroll
    for (int i = 0; i < 4; ++i) async_copy16(ga[i] + kt, lds_a + i * 2048);
#pragma unroll
    for (int i = 0; i < 4; ++i) async_copy16(gb[i] + kt, lds_b + i * 2048);
    __syncthreads();   // compiler drains vmcnt(0) before s_barrier

    f16x8 af[4], bf[4];
#pragma unroll
    for (int mi = 0; mi < 4; ++mi) af[mi] = *(const f16x8*)(paw + mi * 1024 + o0);
#pragma unroll
    for (int ni = 0; ni < 4; ++ni) bf[ni] = *(const f16x8*)(pbw + ni * 1024 + o0);
#pragma unroll
    for (int mi = 0; mi < 4; ++mi)
#pragma unroll
      for (int ni = 0; ni < 4; ++ni)
        acc[mi][ni] = __builtin_amdgcn_mfma_f32_16x16x32_f16(
            af[mi], bf[ni], acc[mi][ni], 0, 0, 0);

#pragma unroll
    for (int mi = 0; mi < 4; ++mi) af[mi] = *(const f16x8*)(paw + mi * 1024 + o1);
#pragma unroll
    for (int ni = 0; ni < 4; ++ni) bf[ni] = *(const f16x8*)(pbw + ni * 1024 + o1);
#pragma unroll
    for (int mi = 0; mi < 4; ++mi)
#pragma unroll
      for (int ni = 0; ni < 4; ++ni)
        acc[mi][ni] = __builtin_amdgcn_mfma_f32_16x16x32_f16(
            af[mi], bf[ni], acc[mi][ni], 0, 0, 0);
  }

  float* Cp = bz ? Cp1 : Cp0;
  // C/D layout: col = lane&15, row = (lane>>4)*4 + r
  const int er = (lane >> 4) * 4;
  const int ec = lane & 15;
#pragma unroll
  for (int mi = 0; mi < 4; ++mi) {
#pragma unroll
    for (int ni = 0; ni < 4; ++ni) {
      long gn = col0 + wn + ni * 16 + ec;
#pragma unroll
      for (int r = 0; r < 4; ++r) {
        long gm = row0 + wm + mi * 16 + er + r;
        Cp[gm * N + gn] = acc[mi][ni][r];
      }
    }
  }
}

// ---------------- plain NT GEMM + bias (GEMM2) -----------------------------
// Same BK=64 swizzled body; grid (32, 16) = 512 blocks (even 2/CU).
// XCD rect swizzle: XCD k owns an 8x8 tile rectangle -> A-rows 2MB + B-cols
// 2MB both fit the 4MB XCD L2.
template<int OUT_IS_F16>
__global__ __launch_bounds__(256, 3) void gemm_nt_bias(
    const half_t* __restrict__ A, const half_t* __restrict__ Bw,
    const float* __restrict__ bias, void* __restrict__ Cout,
    int M, int N, int K)
{
  __shared__ alignas(16) half_t As[128 * 64];   // 16 KB
  __shared__ alignas(16) half_t Bs[128 * 64];   // 16 KB

  const int tid  = threadIdx.x;
  const int lane = tid & 63;
  const int w    = tid >> 6;

  // rect swizzle (GX%4==0, GY%2==0): xcd k -> rect (k&3)*GX/4 x (k>>2)*GY/2
  const int GX = gridDim.x, GY = gridDim.y;
  const int GXq = GX >> 2, GYh = GY >> 1;
  const int flat = blockIdx.x + GX * blockIdx.y;
  const int k8   = flat & 7;
  const int i8   = flat >> 3;
  const int bx = (k8 & 3) * GXq + (i8 % GXq);
  const int by = (k8 >> 2) * GYh + (i8 / GXq);

  const long row0 = (long)by * 128;
  const long col0 = (long)bx * 128;

  const int rr = tid >> 3;
  const int cs = (((tid & 7) ^ (rr & 7)) << 3);
  const half_t* ga[4]; const half_t* gb[4];
#pragma unroll
  for (int i = 0; i < 4; ++i) {
    ga[i] = A  + (row0 + i * 32 + rr) * K + cs;
    gb[i] = Bw + (col0 + i * 32 + rr) * K + cs;
  }
  half_t* lds_a = &As[w * 512];
  half_t* lds_b = &Bs[w * 512];

  const int wm = (w >> 1) * 64;
  const int wn = (w & 1) * 64;
  const int fr   = lane & 15;
  const int quad = lane >> 4;
  const int rsw  = fr & 7;
  const int o0 = ((quad ^ rsw) << 3);
  const int o1 = (((quad | 4) ^ rsw) << 3);
  const half_t* paw = &As[(wm + fr) * 64];
  const half_t* pbw = &Bs[(wn + fr) * 64];

  f32x4 acc[4][4] = {};

  for (int kt = 0; kt < K; kt += 64) {
    __syncthreads();
#pragma unroll
    for (int i = 0; i < 4; ++i) async_copy16(ga[i] + kt, lds_a + i * 2048);
#pragma unroll
    for (int i = 0; i < 4; ++i) async_copy16(gb[i] + kt, lds_b + i * 2048);
    __syncthreads();

    f16x8 af[4], bf[4];
#pragma unroll
    for (int mi = 0; mi < 4; ++mi) af[mi] = *(const f16x8*)(paw + mi * 1024 + o0);
#pragma unroll
    for (int ni = 0; ni < 4; ++ni) bf[ni] = *(const f16x8*)(pbw + ni * 1024 + o0);
#pragma unroll
    for (int mi = 0; mi < 4; ++mi)
#pragma unroll
      for (int ni = 0; ni < 4; ++ni)
        acc[mi][ni] = __builtin_amdgcn_mfma_f32_16x16x32_f16(
            af[mi], bf[ni], acc[mi][ni], 0, 0, 0);

#pragma unroll
    for (int mi = 0; mi < 4; ++mi) af[mi] = *(const f16x8*)(paw + mi * 1024 + o1);
#pragma unroll
    for (int ni = 0; ni < 4; ++ni) bf[ni] = *(const f16x8*)(pbw + ni * 1024 + o1);
#pragma unroll
    for (int mi = 0; mi < 4; ++mi)
#pragma unroll
      for (int ni = 0; ni < 4; ++ni)
        acc[mi][ni] = __builtin_amdgcn_mfma_f32_16x16x32_f16(
            af[mi], bf[ni], acc[mi][ni], 0, 0, 0);
  }

  const int er = (lane >> 4) * 4;
  const int ec = lane & 15;
#pragma unroll
  for (int mi = 0; mi < 4; ++mi) {
#pragma unroll
    for (int ni = 0; ni < 4; ++ni) {
      long gn = col0 + wn + ni * 16 + ec;
      float bv = bias[gn];
#pragma unroll
      for (int r = 0; r < 4; ++r) {
        long gm = row0 + wm + mi * 16 + er + r;
        float v = acc[mi][ni][r] + bv;
        if (OUT_IS_F16) ((half_t*)Cout)[gm * N + gn] = (half_t)v;
        else            ((float*)Cout)[gm * N + gn]  = v;
      }
    }
  }
}

// ---------------- split-K reduce (Q,K cols only): qkvc = f16(C0+C1+bias) ---
// grid (2, 2048); one float4 per thread; partials are L3-hot.
__global__ __launch_bounds__(256) void splitk_reduce_kernel(
    const float4* __restrict__ C0, const float4* __restrict__ C1,
    const float4* __restrict__ bias4, f16x4* __restrict__ dst)
{
  const int col  = blockIdx.x * 256 + threadIdx.x;   // 0..511 (2048 cols /4)
  const long row = blockIdx.y;                       // 0..2047
  const long i   = row * (CQKV / 4) + col;
  float4 a = C0[i];
  float4 b = C1[i];
  float4 bv = bias4[col];
  f16x4 h;
  h.x = (_Float16)(a.x + b.x + bv.x);
  h.y = (_Float16)(a.y + b.y + bv.y);
  h.z = (_Float16)(a.z + b.z + bv.z);
  h.w = (_Float16)(a.w + b.w + bv.w);
  dst[i] = h;
}

// ---------- fused V reduce+transpose: vt[b][d][tok] = f16(C0+C1+bias) ------
__global__ __launch_bounds__(256) void v_reduce_transpose_kernel(
    const float* __restrict__ C0, const float* __restrict__ C1,
    const float* __restrict__ bias, half_t* __restrict__ vt)
{
  __shared__ half_t lt[64][72];
  const int t  = threadIdx.x;
  const int b  = blockIdx.z;
  const int d0 = blockIdx.x * 64;      // dim tile (0..1023)
  const int k0 = blockIdx.y * 64;      // token tile (within batch)
  const int tl = t >> 3;               // 0..31
  const int dc = (t & 7) * 8;          // 0..56

  const long base0 = ((long)b * TT + k0 + tl) * CQKV + 2048 + d0 + dc;
  float4 bv0 = *(const float4*)(bias + 2048 + d0 + dc);
  float4 bv1 = *(const float4*)(bias + 2048 + d0 + dc + 4);
#pragma unroll
  for (int half = 0; half < 2; ++half) {
    const long base = base0 + (long)half * 32 * CQKV;
    float4 a0 = *(const float4*)(C0 + base);
    float4 a1 = *(const float4*)(C0 + base + 4);
    float4 c0 = *(const float4*)(C1 + base);
    float4 c1 = *(const float4*)(C1 + base + 4);
    f16x8 hvec;
    hvec[0] = (_Float16)(a0.x + c0.x + bv0.x);
    hvec[1] = (_Float16)(a0.y + c0.y + bv0.y);
    hvec[2] = (_Float16)(a0.z + c0.z + bv0.z);
    hvec[3] = (_Float16)(a0.w + c0.w + bv0.w);
    hvec[4] = (_Float16)(a1.x + c1.x + bv1.x);
    hvec[5] = (_Float16)(a1.y + c1.y + bv1.y);
    hvec[6] = (_Float16)(a1.z + c1.z + bv1.z);
    hvec[7] = (_Float16)(a1.w + c1.w + bv1.w);
    *(f16x8*)&lt[tl + half * 32][dc] = hvec;
  }
  __syncthreads();

  // lt[a][b] = V[k0+a][d0+b]; write vt[d0+tl][k0+dc+j] = lt[dc+j][tl]
  half_t* dstp = vt + ((long)b * 1024 + d0 + tl) * 1024 + k0 + dc;
  f16x8 o0, o1;
#pragma unroll
  for (int j = 0; j < 8; ++j) {
    o0[j] = lt[dc + j][tl];
    o1[j] = lt[dc + j][tl + 32];
  }
  *(f16x8*)dstp = o0;
  *(f16x8*)(dstp + 32 * 1024) = o1;
}

// ---------------- MFMA flash attention (compact 32-dim heads) --------------
// Block: 256 thr = 4 waves; wave w owns 16 queries. Grid (16, B*NH).
// R6: 2-phase double-buffered K/V (T3-min + T14): issue chunk c+1's
// global_load_lds BEFORE computing chunk c; ONE barrier per chunk whose
// implicit vmcnt(0) drain waits on a prefetch that had the whole compute
// phase to land. Stage into buf^1 is safe: it is issued only after the
// barrier at which every wave finished reading that buffer (compiler emits
// full waitcnt before s_barrier).
// XOR-swizzled packed LDS (rule #21) as R5; l[q] via all-ones A-fragment.
#define PSS 72
__global__ __launch_bounds__(256) void attn_kernel(
    const half_t* __restrict__ qkv,  // [MROWS][3072] (cols 2048.. unused)
    const half_t* __restrict__ vt,   // [BB][1024 d][1024 tok]
    half_t* __restrict__ attc)       // [MROWS][1024]
{
  __shared__ alignas(16) half_t Ks[2][32 * 64];     // 8 KB
  __shared__ alignas(16) half_t Vs[2][32 * 64];     // 8 KB
  __shared__ alignas(16) half_t Ps[4][16 * PSS];    // 9 KB, per-wave

  const int tid  = threadIdx.x;
  const int lane = tid & 63;
  const int w    = tid >> 6;
  const int low  = lane & 15;
  const int quad = lane >> 4;

  // XCD swizzle: flat -> (tile, bh) with heads chunked per XCD
  const int flat = blockIdx.x + 16 * blockIdx.y;   // 0..1023
  const int swz  = (flat & 7) * 128 + (flat >> 3);
  const int tile = swz & 15;
  const int bh   = swz >> 4;
  const int b    = bh >> 5;
  const int h    = bh & 31;
  const long rb  = (long)b * TT;

  // staging source addresses (per thread); LDS dest linear: t -> t*16B
  const int su  = tid >> 3;              // LDS row (K: u=key>>1, V: d)
  const int sp  = tid & 7;               // stored chunk position
  const int spx = sp ^ (su & 7);         // source chunk
  // K: key = 2u + (spx>>2), d-chunk = spx&3
  const half_t* kg = qkv + (rb + 2 * su + (spx >> 2)) * CQKV + 1024
                         + h * 32 + (spx & 3) * 8;
  // V: vt row d = h*32 + su, key offset spx*8
  const half_t* vg = vt + ((long)b * 1024 + h * 32 + su) * 1024 + spx * 8;
  half_t* kd0 = &Ks[0][w * 512];         // wave-uniform; HW adds lane*16B
  half_t* kd1 = &Ks[1][w * 512];
  half_t* vd0 = &Vs[0][w * 512];
  half_t* vd1 = &Vs[1][w * 512];
  half_t* psw = &Ps[w][0];
  float*  Ob  = (float*)psw;             // epilogue overlay [q][36 floats]

  const int t0 = tile * 64;
  const int qg = t0 + 16 * w;

  // Q fragment: A[m=low][k=quad*8+j]
  f16x8 qf = *(const f16x8*)&qkv[(rb + qg + low) * CQKV + h * 32 + quad * 8];

  // all-ones A-fragment: D[m][n] = sum_k P[n][k] = l[n] for every m
  f16x8 onesf;
#pragma unroll
  for (int i = 0; i < 8; ++i) onesf[i] = (_Float16)1.0f;

  f32x4 acc0 = {}, acc1 = {}, acc2 = {};
  const f32x4 zero = {};

  const int dsw = low & 7;
  const int ksw = (low >> 1) & 7;
  const int kp  = (((low & 1) << 2) | quad) ^ ksw;   // Ks read chunk pos

  // ---- prologue: stage chunk 0 into buf 0 ----
  async_copy16(kg, kd0);
  async_copy16(vg, vd0);
  __syncthreads();     // drains vmcnt(0): chunk 0 resident

  int cur = 0;
  for (int c = 0; ; c += 64) {
    const bool last = (c == t0);
    // issue next chunk's loads into the other buffer (overlaps compute)
    if (!last) {
      async_copy16(kg + (long)(c + 64) * CQKV, cur ? kd0 : kd1);
      async_copy16(vg + (c + 64),              cur ? vd0 : vd1);
    }
    const half_t* Kb = cur ? &Ks[1][0] : &Ks[0][0];
    const half_t* Vb = cur ? &Vs[1][0] : &Vs[0][0];

    // S = Q.K^T : C[m=q][n=key]
    f32x4 s[4];
#pragma unroll
    for (int st = 0; st < 4; ++st) {
      const int u = st * 8 + (low >> 1);
      f16x8 kf = *(const f16x8*)&Kb[u * 64 + kp * 8];
      s[st] = __builtin_amdgcn_mfma_f32_16x16x32_f16(qf, kf, zero, 0, 0, 0);
    }

    // P = exp2(S) (causal mask only at diagonal chunk), write to LDS
    const bool diag = last;
#pragma unroll
    for (int st = 0; st < 4; ++st) {
#pragma unroll
      for (int r = 0; r < 4; ++r) {
        const int key = c + st * 16 + low;
        const int q   = qg + 4 * quad + r;
        float p = __builtin_amdgcn_exp2f(s[st][r]);
        if (diag && key > q) p = 0.f;
        psw[(4 * quad + r) * PSS + st * 16 + low] = (_Float16)p;
      }
    }

    // P frags (B: [n=q][k=key])
    f16x8 p0 = *(const f16x8*)&psw[low * PSS + 0 * 32 + quad * 8];
    f16x8 p1 = *(const f16x8*)&psw[low * PSS + 1 * 32 + quad * 8];

    // Vs frags (A: [m=d][k=key]), swizzled chunk reads
    f16x8 v00 = *(const f16x8*)&Vb[(0  + low) * 64 + ((0 + quad) ^ dsw) * 8];
    f16x8 v01 = *(const f16x8*)&Vb[(0  + low) * 64 + ((4 + quad) ^ dsw) * 8];
    f16x8 v10 = *(const f16x8*)&Vb[(16 + low) * 64 + ((0 + quad) ^ dsw) * 8];
    f16x8 v11 = *(const f16x8*)&Vb[(16 + low) * 64 + ((4 + quad) ^ dsw) * 8];

    acc0 = __builtin_amdgcn_mfma_f32_16x16x32_f16(v00,   p0, acc0, 0, 0, 0);
    acc0 = __builtin_amdgcn_mfma_f32_16x16x32_f16(v01,   p1, acc0, 0, 0, 0);
    acc1 = __builtin_amdgcn_mfma_f32_16x16x32_f16(v10,   p0, acc1, 0, 0, 0);
    acc1 = __builtin_amdgcn_mfma_f32_16x16x32_f16(v11,   p1, acc1, 0, 0, 0);
    acc2 = __builtin_amdgcn_mfma_f32_16x16x32_f16(onesf, p0, acc2, 0, 0, 0);
    acc2 = __builtin_amdgcn_mfma_f32_16x16x32_f16(onesf, p1, acc2, 0, 0, 0);

    if (last) break;
    __syncthreads();   // prefetch resident (vmcnt 0) + all reads of buf done
    cur ^= 1;
  }

  // ---- epilogue ----
  __syncthreads();   // last chunk's Ps reads done before Ob overlay writes

  // every lane's acc2[r] = l[q = lane&15]
  float linv = 1.0f / acc2[0];

  // O^T[d=16t+4quad+r][q=low] -> Ob[q][d], scaled
#pragma unroll
  for (int r = 0; r < 4; ++r) {
    Ob[low * 36 + 0  + 4 * quad + r] = acc0[r] * linv;
    Ob[low * 36 + 16 + 4 * quad + r] = acc1[r] * linv;
  }
  __syncthreads();

  // row-wise readback: lane (q=low, dblk=quad) -> 8 contiguous dims
  f16x8 ov;
#pragma unroll
  for (int i = 0; i < 8; ++i)
    ov[i] = (_Float16)Ob[low * 36 + quad * 8 + i];
  *(f16x8*)&attc[(rb + qg + low) * 1024 + h * 32 + quad * 8] = ov;
}

// ---------------- launcher ----------------
extern "C" void kernel_launch(void* const* d_in, const int* in_sizes, int n_in,
                              void* d_out, int out_size, void* d_ws, size_t ws_size,
                              hipStream_t stream) {
  (void)in_sizes; (void)n_in; (void)out_size; (void)ws_size;
  const float* x  = (const float*)d_in[0];
  const float* W1 = (const float*)d_in[1];
  const float* b1 = (const float*)d_in[2];
  const float* W2 = (const float*)d_in[3];
  const float* b2 = (const float*)d_in[4];
  float* out = (float*)d_out;

  const size_t nX   = (size_t)MROWS * DIMX;   //  8,388,608
  const size_t nW1f = (size_t)CQKV  * DIMX;   // 12,582,912
  const size_t nW2f = (size_t)DIMX  * 1024;   //  4,194,304
  const size_t nQKV = (size_t)MROWS * CQKV;   //  6,291,456
  const size_t nATT = (size_t)MROWS * 1024;   //  2,097,152

  half_t* ws   = (half_t*)d_ws;
  half_t* xh   = ws;
  half_t* w1f  = xh   + nX;
  half_t* w2f  = w1f  + nW1f;
  half_t* qkvc = w2f  + nW2f;
  half_t* attc = qkvc + nQKV;
  float*  b1f  = (float*)(attc + nATT);       // 3072 floats
  // split-K partials: C0 reuses d_out (2048*4096 f32 >= 2048*3072 f32,
  // fully overwritten by GEMM2 at the end); C1 in workspace tail.
  float*  c1   = (float*)(b1f + 4096);        // 16B-aligned; 25.2 MB
  // V^T [2][1024][1024] f16 (4 MB) overlays xh — dead after GEMM1.
  half_t* vt   = xh;

  cvt_f32_f16_kernel<<<4096, 256, 0, stream>>>((const float4*)x, (f16x4*)xh,
                                               (int)(nX / 4));
  fold_w1_kernel<<<12288, 256, 0, stream>>>(W1, b1, w1f, b1f);
  fold_w2_kernel<<<4096, 256, 0, stream>>>(W2, w2f);

  // GEMM1: split-K=2 -> 768 blocks (3/CU) of 128x128x2048 partials
  gemm_nt_splitk<<<dim3(CQKV / 128, MROWS / 128, 2), 256, 0, stream>>>(
      xh, w1f, out /*C0*/, c1 /*C1*/, MROWS, CQKV, DIMX);

  // Q,K cols -> qkvc; V cols -> vt (fused reduce+transpose)
  splitk_reduce_kernel<<<dim3(2, MROWS), 256, 0, stream>>>(
      (const float4*)out, (const float4*)c1, (const float4*)b1f,
      (f16x4*)qkvc);
  v_reduce_transpose_kernel<<<dim3(16, 16, BB), 256, 0, stream>>>(
      out, c1, b1f, vt);

  attn_kernel<<<dim3(16, BB * NH), 256, 0, stream>>>(qkvc, vt, attc);

  gemm_nt_bias<0><<<dim3(DIMX / 128, MROWS / 128), 256, 0, stream>>>(
      attc, w2f, b2, (void*)out, MROWS, DIMX, 1024);
}